// Round 4
// baseline (161.994 us; speedup 1.0000x reference)
//
#include <hip/hip_runtime.h>

// Enframe: out[bc, k, t] = x[bc, t*HOP + k].  BC=16, S=480000, FL=2048,
// HOP=512, T=934.  k = h*HOP + r:  out[bc, h*HOP+r, t] = y[t+h, r],
// y = x as rows of HOP floats.
//
// R3 lesson: tiled-transpose kernel stuck ~2-3x over the 24us traffic floor.
// Suspects: cross-block partial-line writes (row stride 3736B, 256B segments
// never line-aligned -> RMW when the neighbor tile's partial evicts) and
// exposed HBM latency (load->barrier->store per tiny block).
// This version:
//  - block owns (bc, 16 r-values, all 4 h) x a contiguous half of t, looping
//    t-chunks of 64 inside the block -> every output line completed by the
//    SAME block within ~us -> L2 merges partials; no cross-block RMW.
//  - register prefetch: next chunk's loads issued before the store phase and
//    held in VGPRs across it (LDS prefetch is defeated by the vmcnt(0) drain
//    at s_barrier; registers bypass the barrier).
//  - loads: 16 aligned 64B lines per wave instr; each input line fetched once.
//  - LDS stride 17: store-phase column reads hit 32 banks 2-way (free).

constexpr int FL   = 2048;
constexpr int HOP  = 512;
constexpr int RT   = 16;        // r-values per block
constexpr int TT   = 64;        // t per chunk
constexpr int ROWS = TT + 3;    // 67 rows (t..t+3 halo)
constexpr int LSTR = RT + 1;    // 17

__global__ __launch_bounds__(256)
void enframe_kernel(const float* __restrict__ x, float* __restrict__ out,
                    int S, int T) {
    __shared__ float lds[ROWS * LSTR];

    const int bc = blockIdx.x;            // 0..15
    const int r0 = blockIdx.y * RT;       // 0..511 step 16
    const int th = blockIdx.z;            // t-half: 0 or 1
    const int nch  = (T + TT - 1) / TT;   // 15
    const int half = (nch + 1) / 2;       // 8
    const int c_begin = th * half;
    const int c_end   = th ? nch : half;

    const int tid = threadIdx.x;
    const float* xb = x + (size_t)bc * S;
    float* ob = out + (size_t)bc * FL * T;
    const int max_row = S / HOP - 1;      // last fully-inside y-row (936)

    const int lrow = tid >> 2;            // 0..63
    const int lrg  = (tid & 3) * 4;       // float4 col within 16-float row
    const bool tail = tid < (ROWS - 64) * 4;   // 12 threads load rows 64..66
    const int trow2 = 64 + (tid >> 2);

    // prefetch first chunk into registers
    float4 a0 = {0,0,0,0}, a1 = {0,0,0,0};
    {
        const int t0 = c_begin * TT;
        const int tr = t0 + lrow;
        if (tr <= max_row) a0 = *(const float4*)(xb + (size_t)tr * HOP + r0 + lrg);
        if (tail) {
            const int tr2 = t0 + trow2;
            if (tr2 <= max_row) a1 = *(const float4*)(xb + (size_t)tr2 * HOP + r0 + lrg);
        }
    }

    for (int c = c_begin; c < c_end; ++c) {
        if (c > c_begin) __syncthreads();     // store-phase reads of prev chunk done
        {   // registers -> LDS
            float* l = lds + lrow * LSTR + lrg;
            l[0] = a0.x; l[1] = a0.y; l[2] = a0.z; l[3] = a0.w;
            if (tail) {
                float* l2 = lds + trow2 * LSTR + lrg;
                l2[0] = a1.x; l2[1] = a1.y; l2[2] = a1.z; l2[3] = a1.w;
            }
        }
        __syncthreads();

        // issue next chunk's loads; they fly during the store phase
        if (c + 1 < c_end) {
            const int t0n = (c + 1) * TT;
            const int tr = t0n + lrow;
            a0 = (tr <= max_row) ? *(const float4*)(xb + (size_t)tr * HOP + r0 + lrg)
                                 : float4{0,0,0,0};
            if (tail) {
                const int tr2 = t0n + trow2;
                a1 = (tr2 <= max_row) ? *(const float4*)(xb + (size_t)tr2 * HOP + r0 + lrg)
                                      : float4{0,0,0,0};
            }
        }

        // store phase: 64 rows (4h x 16r) x 64 t, lanes along t
        const int t0 = c * TT;
        const int r  = tid >> 4;              // 0..15
        const int tl = (tid & 15) * 4;        // local t
        const bool full = (t0 + TT <= T);
#pragma unroll
        for (int h = 0; h < 4; ++h) {
            const float* l = lds + (tl + h) * LSTR + r;
            float* op = ob + (size_t)(h * HOP + r0 + r) * T + t0 + tl;
            if (full) {
                float4 v = { l[0], l[LSTR], l[2 * LSTR], l[3 * LSTR] };
                *(float4*)op = v;
            } else {
#pragma unroll
                for (int j = 0; j < 4; ++j)
                    if (t0 + tl + j < T) op[j] = l[j * LSTR];
            }
        }
    }
}

extern "C" void kernel_launch(void* const* d_in, const int* in_sizes, int n_in,
                              void* d_out, int out_size, void* d_ws, size_t ws_size,
                              hipStream_t stream) {
    const float* x = (const float*)d_in[0];
    float* out = (float*)d_out;
    const int BC = 16;                  // B*C = 8*2
    const int S  = in_sizes[0] / BC;    // 480000
    const int T  = (S - FL) / HOP + 1;  // 934
    dim3 grid(BC, HOP / RT, 2);         // 16 x 32 x 2 = 1024 blocks (4/CU)
    enframe_kernel<<<grid, 256, 0, stream>>>(x, out, S, T);
}